// Round 1
// baseline (1157.682 us; speedup 1.0000x reference)
//
#include <hip/hip_runtime.h>

#define TT   512
#define DIN  2048
#define NH1  128
#define NH2  64
#define NF1  32
#define NB   64

__device__ __forceinline__ float tanh_fast(float x) {
    x = fminf(fmaxf(x, -15.0f), 15.0f);
    float e = __expf(2.0f * x);
    return (e - 1.0f) / (e + 1.0f);
}

// ---------------------------------------------------------------------------
// Kernel A: xp1[m][i] = sum_d x[m][d] * W_ih1[i][d] + b_ih1[i] + b_hh1[i]
// M = 32768 (b*t), K = 2048, N = 128. fp32, LDS-tiled, BM=64, KC=32.
// 256 threads, micro-tile 4(M) x 8(N) per thread.
// ---------------------------------------------------------------------------
__global__ __launch_bounds__(256) void xp1_gemm(const float* __restrict__ x,
                                                const float* __restrict__ Wih1,
                                                const float* __restrict__ bih1,
                                                const float* __restrict__ bhh1,
                                                float* __restrict__ xp1) {
    __shared__ __align__(16) float xs[32 * 64];    // [k][m] k-major
    __shared__ __align__(16) float ws[32 * 128];   // [k][n] k-major

    const int tid = threadIdx.x;
    const int m0  = blockIdx.x * 64;
    const int rg  = tid >> 4;    // 0..15 -> rows rg*4..+3
    const int cg  = tid & 15;    // 0..15 -> cols cg*8..+7

    float bias[8];
#pragma unroll
    for (int j = 0; j < 8; ++j)
        bias[j] = bih1[cg * 8 + j] + bhh1[cg * 8 + j];

    float acc[4][8];
#pragma unroll
    for (int i = 0; i < 4; ++i)
#pragma unroll
        for (int j = 0; j < 8; ++j) acc[i][j] = 0.0f;

    for (int kc = 0; kc < DIN; kc += 32) {
        // stage x tile (64 rows x 32 k) = 512 float4, 2 per thread
#pragma unroll
        for (int q = 0; q < 2; ++q) {
            int f = tid + q * 256;
            int row = f >> 3, kq = f & 7;
            float4 v = *(const float4*)&x[(size_t)(m0 + row) * DIN + kc + kq * 4];
            xs[(kq * 4 + 0) * 64 + row] = v.x;
            xs[(kq * 4 + 1) * 64 + row] = v.y;
            xs[(kq * 4 + 2) * 64 + row] = v.z;
            xs[(kq * 4 + 3) * 64 + row] = v.w;
        }
        // stage W tile (128 rows x 32 k) = 1024 float4, 4 per thread
#pragma unroll
        for (int q = 0; q < 4; ++q) {
            int f = tid + q * 256;
            int row = f >> 3, kq = f & 7;
            float4 v = *(const float4*)&Wih1[(size_t)row * DIN + kc + kq * 4];
            ws[(kq * 4 + 0) * 128 + row] = v.x;
            ws[(kq * 4 + 1) * 128 + row] = v.y;
            ws[(kq * 4 + 2) * 128 + row] = v.z;
            ws[(kq * 4 + 3) * 128 + row] = v.w;
        }
        __syncthreads();

#pragma unroll 8
        for (int k = 0; k < 32; ++k) {
            float4 av = *(const float4*)&xs[k * 64 + rg * 4];
            float4 b0 = *(const float4*)&ws[k * 128 + cg * 8];
            float4 b1 = *(const float4*)&ws[k * 128 + cg * 8 + 4];
            float a[4]  = {av.x, av.y, av.z, av.w};
            float bb[8] = {b0.x, b0.y, b0.z, b0.w, b1.x, b1.y, b1.z, b1.w};
#pragma unroll
            for (int i = 0; i < 4; ++i)
#pragma unroll
                for (int j = 0; j < 8; ++j)
                    acc[i][j] = fmaf(a[i], bb[j], acc[i][j]);
        }
        __syncthreads();
    }

#pragma unroll
    for (int i = 0; i < 4; ++i) {
        size_t m = (size_t)(m0 + rg * 4 + i);
        float4 o0 = make_float4(acc[i][0] + bias[0], acc[i][1] + bias[1],
                                acc[i][2] + bias[2], acc[i][3] + bias[3]);
        float4 o1 = make_float4(acc[i][4] + bias[4], acc[i][5] + bias[5],
                                acc[i][6] + bias[6], acc[i][7] + bias[7]);
        *(float4*)&xp1[m * NH1 + cg * 8]     = o0;
        *(float4*)&xp1[m * NH1 + cg * 8 + 4] = o1;
    }
}

// ---------------------------------------------------------------------------
// Kernel B: fused 2-layer scan + FC head. One block per batch element.
// 256 threads: tid 0..127 (waves 0,1) own W_hh1 row tid, compute h1.
//              tid 128..191 (wave 2)  own W_ih2 row,     compute xp2 & h2.
//              tid 192..255 (wave 3)  own W_hh2 row,     compute recurrent y2.
// Layer-2 lags layer-1 by one step so both run concurrently each iteration.
// Step s (1..513): waves01 make H1[s] (s<=512); waves2/3 make H2[s-1] (s>=2).
// Weights in VGPRs; h-state broadcast from LDS (ds_read_b128, same-addr).
// ---------------------------------------------------------------------------
__global__ __launch_bounds__(256, 1) void rnn_scan(
        const float* __restrict__ xp1,  const float* __restrict__ Whh1,
        const float* __restrict__ Wih2, const float* __restrict__ Whh2,
        const float* __restrict__ bih2, const float* __restrict__ bhh2,
        const float* __restrict__ Wfc1, const float* __restrict__ bfc1,
        const float* __restrict__ Wfc2, const float* __restrict__ bfc2,
        float* __restrict__ out) {
    __shared__ __align__(16) float h1buf[2][NH1];
    __shared__ __align__(16) float h2buf[2][NH2];
    __shared__ __align__(16) float y2buf[NH2];

    const int tid = threadIdx.x;
    const int b   = blockIdx.x;

    float wrow[128];
    float b2 = 0.0f;
    if (tid < 128) {
        const float4* src = (const float4*)(Whh1 + (size_t)tid * NH1);
#pragma unroll
        for (int i = 0; i < 32; ++i) {
            float4 v = src[i];
            wrow[4*i+0] = v.x; wrow[4*i+1] = v.y;
            wrow[4*i+2] = v.z; wrow[4*i+3] = v.w;
        }
    } else if (tid < 192) {
        const float4* src = (const float4*)(Wih2 + (size_t)(tid - 128) * NH1);
#pragma unroll
        for (int i = 0; i < 32; ++i) {
            float4 v = src[i];
            wrow[4*i+0] = v.x; wrow[4*i+1] = v.y;
            wrow[4*i+2] = v.z; wrow[4*i+3] = v.w;
        }
    } else {
        const int j = tid - 192;
        const float4* src = (const float4*)(Whh2 + (size_t)j * NH2);
#pragma unroll
        for (int i = 0; i < 16; ++i) {
            float4 v = src[i];
            wrow[4*i+0] = v.x; wrow[4*i+1] = v.y;
            wrow[4*i+2] = v.z; wrow[4*i+3] = v.w;
        }
        b2 = bih2[j] + bhh2[j];
    }

    if (tid < 128) { h1buf[0][tid] = 0.0f; h1buf[1][tid] = 0.0f; }
    if (tid < 64)  { h2buf[0][tid] = 0.0f; h2buf[1][tid] = 0.0f; y2buf[tid] = 0.0f; }
    __syncthreads();

    float xpv = 0.0f;
    if (tid < 128) xpv = xp1[((size_t)b * TT + 0) * NH1 + tid];
    float xp2acc = 0.0f;
    int cur = 0;

    for (int s = 1; s <= TT + 1; ++s) {
        const int nxt = cur ^ 1;
        if (tid < 128) {
            if (s <= TT) {
                float xpn = 0.0f;
                if (s < TT) xpn = xp1[((size_t)b * TT + s) * NH1 + tid];  // prefetch
                float a0 = 0.f, a1 = 0.f, a2 = 0.f, a3 = 0.f;
                const float* hb = h1buf[cur];
#pragma unroll
                for (int k4 = 0; k4 < 32; ++k4) {
                    float4 h = *(const float4*)&hb[k4 * 4];
                    a0 = fmaf(wrow[4*k4+0], h.x, a0);
                    a1 = fmaf(wrow[4*k4+1], h.y, a1);
                    a2 = fmaf(wrow[4*k4+2], h.z, a2);
                    a3 = fmaf(wrow[4*k4+3], h.w, a3);
                }
                h1buf[nxt][tid] = tanh_fast(xpv + ((a0 + a1) + (a2 + a3)));
                xpv = xpn;
            }
        } else if (tid < 192) {
            if (s >= 2) {
                float a0 = 0.f, a1 = 0.f, a2 = 0.f, a3 = 0.f;
                const float* hb = h1buf[cur];   // = H1[s-1]
#pragma unroll
                for (int k4 = 0; k4 < 32; ++k4) {
                    float4 h = *(const float4*)&hb[k4 * 4];
                    a0 = fmaf(wrow[4*k4+0], h.x, a0);
                    a1 = fmaf(wrow[4*k4+1], h.y, a1);
                    a2 = fmaf(wrow[4*k4+2], h.z, a2);
                    a3 = fmaf(wrow[4*k4+3], h.w, a3);
                }
                xp2acc = (a0 + a1) + (a2 + a3);
            }
        } else {
            if (s >= 2) {
                float a0 = 0.f, a1 = 0.f, a2 = 0.f, a3 = 0.f;
                const float* hb = h2buf[cur];   // = H2[s-2]
#pragma unroll
                for (int k4 = 0; k4 < 16; ++k4) {
                    float4 h = *(const float4*)&hb[k4 * 4];
                    a0 = fmaf(wrow[4*k4+0], h.x, a0);
                    a1 = fmaf(wrow[4*k4+1], h.y, a1);
                    a2 = fmaf(wrow[4*k4+2], h.z, a2);
                    a3 = fmaf(wrow[4*k4+3], h.w, a3);
                }
                y2buf[tid - 192] = (a0 + a1) + (a2 + a3) + b2;
            }
        }
        __syncthreads();
        if (tid >= 128 && tid < 192 && s >= 2) {
            const int j = tid - 128;
            h2buf[nxt][j] = tanh_fast(xp2acc + y2buf[j]);   // H2[s-1]
        }
        __syncthreads();
        cur = nxt;
    }

    // FC head: h2buf[cur] = H2[512]. wave 0 only.
    if (tid < 64) {
        float v = 0.0f;
        if (tid < 32) {
            float a = bfc1[tid];
            const float* hb = h2buf[cur];
#pragma unroll
            for (int k = 0; k < 64; ++k)
                a = fmaf(Wfc1[tid * 64 + k], hb[k], a);
            v = fmaxf(a, 0.0f) * Wfc2[tid];
        }
#pragma unroll
        for (int off = 32; off > 0; off >>= 1) v += __shfl_down(v, off);
        if (tid == 0) out[b] = v + bfc2[0];
    }
}

extern "C" void kernel_launch(void* const* d_in, const int* in_sizes, int n_in,
                              void* d_out, int out_size, void* d_ws, size_t ws_size,
                              hipStream_t stream) {
    const float* x     = (const float*)d_in[0];
    const float* Wih1  = (const float*)d_in[1];
    const float* Whh1  = (const float*)d_in[2];
    const float* bih1  = (const float*)d_in[3];
    const float* bhh1  = (const float*)d_in[4];
    const float* Wih2  = (const float*)d_in[5];
    const float* Whh2  = (const float*)d_in[6];
    const float* bih2  = (const float*)d_in[7];
    const float* bhh2  = (const float*)d_in[8];
    const float* Wfc1  = (const float*)d_in[9];
    const float* bfc1  = (const float*)d_in[10];
    const float* Wfc2  = (const float*)d_in[11];
    const float* bfc2  = (const float*)d_in[12];
    float* outp = (float*)d_out;

    float* xp1 = (float*)d_ws;   // 32768 x 128 fp32 = 16 MB

    xp1_gemm<<<dim3((NB * TT) / 64), dim3(256), 0, stream>>>(x, Wih1, bih1, bhh1, xp1);
    rnn_scan<<<dim3(NB), dim3(256), 0, stream>>>(xp1, Whh1, Wih2, Whh2, bih2, bhh2,
                                                 Wfc1, bfc1, Wfc2, bfc2, outp);
}

// Round 2
// 1054.662 us; speedup vs baseline: 1.0977x; 1.0977x over previous
//
#include <hip/hip_runtime.h>

#define TT   512
#define DIN  2048
#define NH1  128
#define NH2  64
#define NF1  32
#define NB   64

__device__ __forceinline__ float tanh_fast(float x) {
    x = fminf(fmaxf(x, -15.0f), 15.0f);
    float e = __expf(2.0f * x);
    return (e - 1.0f) / (e + 1.0f);
}

__device__ __forceinline__ float rlane(float v, int l) {
    return __int_as_float(__builtin_amdgcn_readlane(__float_as_int(v), l));
}

// ---------------------------------------------------------------------------
// Kernel A: xp1[m][n] = sum_d x[m][d]*W_ih1[n][d] + b_ih1[n] + b_hh1[n]
// M=32768, K=2048, N=128. BM=128, BK=32, 256 threads, micro 8x8.
// k-major LDS tiles; ws uses a 12-stride interleave (col 8n+j -> 12n+j) so
// the 16 n-group b128 reads land on distinct bank groups (2-way max = free).
// ---------------------------------------------------------------------------
__global__ __launch_bounds__(256) void xp1_gemm(const float* __restrict__ x,
                                                const float* __restrict__ Wih1,
                                                const float* __restrict__ bih1,
                                                const float* __restrict__ bhh1,
                                                float* __restrict__ xp1) {
    __shared__ __align__(16) float xs[32][128];   // [k][m]
    __shared__ __align__(16) float ws[32][188];   // [k][n'] n' = 12*(n>>3)+(n&7)

    const int tid = threadIdx.x;
    const int m0  = blockIdx.x * 128;
    const int mg  = tid >> 4;    // 0..15 -> rows mg*8..+7
    const int ng  = tid & 15;    // 0..15 -> cols ng*8..+7

    float bias[8];
#pragma unroll
    for (int j = 0; j < 8; ++j)
        bias[j] = bih1[ng * 8 + j] + bhh1[ng * 8 + j];

    float acc[8][8];
#pragma unroll
    for (int i = 0; i < 8; ++i)
#pragma unroll
        for (int j = 0; j < 8; ++j) acc[i][j] = 0.0f;

    for (int kc = 0; kc < DIN; kc += 32) {
        // stage x tile: 128 rows x 32 k = 1024 float4, 4 per thread
#pragma unroll
        for (int q = 0; q < 4; ++q) {
            int f = tid + q * 256;
            int row = f >> 3, kq = f & 7;
            float4 v = *(const float4*)&x[(size_t)(m0 + row) * DIN + kc + kq * 4];
            xs[kq * 4 + 0][row] = v.x;
            xs[kq * 4 + 1][row] = v.y;
            xs[kq * 4 + 2][row] = v.z;
            xs[kq * 4 + 3][row] = v.w;
        }
        // stage W tile: 128 rows x 32 k, interleaved col map
#pragma unroll
        for (int q = 0; q < 4; ++q) {
            int f = tid + q * 256;
            int row = f >> 3, kq = f & 7;
            int rp = 12 * (row >> 3) + (row & 7);
            float4 v = *(const float4*)&Wih1[(size_t)row * DIN + kc + kq * 4];
            ws[kq * 4 + 0][rp] = v.x;
            ws[kq * 4 + 1][rp] = v.y;
            ws[kq * 4 + 2][rp] = v.z;
            ws[kq * 4 + 3][rp] = v.w;
        }
        __syncthreads();

#pragma unroll 4
        for (int k = 0; k < 32; ++k) {
            float4 a0 = *(const float4*)&xs[k][mg * 8];
            float4 a1 = *(const float4*)&xs[k][mg * 8 + 4];
            float4 b0 = *(const float4*)&ws[k][12 * ng];
            float4 b1 = *(const float4*)&ws[k][12 * ng + 4];
            float av[8] = {a0.x, a0.y, a0.z, a0.w, a1.x, a1.y, a1.z, a1.w};
            float bv[8] = {b0.x, b0.y, b0.z, b0.w, b1.x, b1.y, b1.z, b1.w};
#pragma unroll
            for (int i = 0; i < 8; ++i)
#pragma unroll
                for (int j = 0; j < 8; ++j)
                    acc[i][j] = fmaf(av[i], bv[j], acc[i][j]);
        }
        __syncthreads();
    }

#pragma unroll
    for (int i = 0; i < 8; ++i) {
        size_t m = (size_t)(m0 + mg * 8 + i);
        float4 o0 = make_float4(acc[i][0] + bias[0], acc[i][1] + bias[1],
                                acc[i][2] + bias[2], acc[i][3] + bias[3]);
        float4 o1 = make_float4(acc[i][4] + bias[4], acc[i][5] + bias[5],
                                acc[i][6] + bias[6], acc[i][7] + bias[7]);
        *(float4*)&xp1[m * NH1 + ng * 8]     = o0;
        *(float4*)&xp1[m * NH1 + ng * 8 + 4] = o1;
    }
}

// ---------------------------------------------------------------------------
// Kernel B: fused 2-layer scan + FC head. One block (=1 CU) per batch elem.
// 256 threads = 4 waves = exactly 1 wave per SIMD (VALU-parallel).
// h-broadcast via v_readlane (VALU) instead of LDS b128 broadcast: each wave
// reads the h1 vector ONCE as a lane-spread float2 (1 ds_read_b64), then
// broadcasts per-k with readlane feeding v_fmac (SGPR operand).
//   wave0: H1 rows 0-63     wave1: H1 rows 64-127
//   wave2: xp2[t] = Wih2 . H1[t] (+bias), 1 step behind, parity LDS buffer
//   wave3: full h2 chain (state in wave3 registers, readlane broadcast),
//          2 steps behind; FC head at the end, no extra barriers.
// ONE __syncthreads per step.
// ---------------------------------------------------------------------------
__global__ __launch_bounds__(256, 1) void rnn_scan(
        const float* __restrict__ xp1,  const float* __restrict__ Whh1,
        const float* __restrict__ Wih2, const float* __restrict__ Whh2,
        const float* __restrict__ bih2, const float* __restrict__ bhh2,
        const float* __restrict__ Wfc1, const float* __restrict__ bfc1,
        const float* __restrict__ Wfc2, const float* __restrict__ bfc2,
        float* __restrict__ out) {
    __shared__ __align__(16) float h1buf[2][NH1];
    __shared__ __align__(16) float xp2buf[2][NH2];

    const int tid  = threadIdx.x;
    const int lane = tid & 63;
    const int wv   = tid >> 6;
    const int b    = blockIdx.x;

    float wrow[128];
    float wfc[64];
    float b2 = 0.0f;

    if (wv <= 1) {
        const int row = wv * 64 + lane;
        const float4* src = (const float4*)(Whh1 + (size_t)row * NH1);
#pragma unroll
        for (int i = 0; i < 32; ++i) {
            float4 v = src[i];
            wrow[4*i+0] = v.x; wrow[4*i+1] = v.y;
            wrow[4*i+2] = v.z; wrow[4*i+3] = v.w;
        }
    } else if (wv == 2) {
        const float4* src = (const float4*)(Wih2 + (size_t)lane * NH1);
#pragma unroll
        for (int i = 0; i < 32; ++i) {
            float4 v = src[i];
            wrow[4*i+0] = v.x; wrow[4*i+1] = v.y;
            wrow[4*i+2] = v.z; wrow[4*i+3] = v.w;
        }
        b2 = bih2[lane] + bhh2[lane];
    } else {
        const float4* src = (const float4*)(Whh2 + (size_t)lane * NH2);
#pragma unroll
        for (int i = 0; i < 16; ++i) {
            float4 v = src[i];
            wrow[4*i+0] = v.x; wrow[4*i+1] = v.y;
            wrow[4*i+2] = v.z; wrow[4*i+3] = v.w;
        }
        const int fr = lane & 31;   // lanes 32-63 load a valid dup row
        const float4* fsrc = (const float4*)(Wfc1 + (size_t)fr * NH2);
#pragma unroll
        for (int i = 0; i < 16; ++i) {
            float4 v = fsrc[i];
            wfc[4*i+0] = v.x; wfc[4*i+1] = v.y;
            wfc[4*i+2] = v.z; wfc[4*i+3] = v.w;
        }
    }

    if (tid < 128) h1buf[0][tid] = 0.0f;
    __syncthreads();

    float xpv = 0.0f;
    if (wv <= 1) xpv = xp1[((size_t)b * TT + 0) * NH1 + wv * 64 + lane];
    float h2prev = 0.0f;
    int cur = 0;

    for (int s = 1; s <= TT + 2; ++s) {
        const int nxt = cur ^ 1;
        if (wv <= 1) {
            if (s <= TT) {
                const int row = wv * 64 + lane;
                float2 hh = *(const float2*)&h1buf[cur][2 * lane];
                float xpn = 0.0f;
                if (s < TT) xpn = xp1[((size_t)b * TT + s) * NH1 + row];
                float a0 = xpv, a1 = 0.f, a2 = 0.f, a3 = 0.f;
#pragma unroll
                for (int l = 0; l < 64; l += 2) {
                    float he0 = rlane(hh.x, l),     ho0 = rlane(hh.y, l);
                    float he1 = rlane(hh.x, l + 1), ho1 = rlane(hh.y, l + 1);
                    a0 = fmaf(wrow[2*l],     he0, a0);
                    a1 = fmaf(wrow[2*l + 1], ho0, a1);
                    a2 = fmaf(wrow[2*l + 2], he1, a2);
                    a3 = fmaf(wrow[2*l + 3], ho1, a3);
                }
                h1buf[nxt][row] = tanh_fast((a0 + a1) + (a2 + a3));
                xpv = xpn;
            }
        } else if (wv == 2) {
            if (s >= 2 && s <= TT + 1) {
                float2 hh = *(const float2*)&h1buf[cur][2 * lane];  // = H1[s-1]
                float a0 = b2, a1 = 0.f, a2 = 0.f, a3 = 0.f;
#pragma unroll
                for (int l = 0; l < 64; l += 2) {
                    float he0 = rlane(hh.x, l),     ho0 = rlane(hh.y, l);
                    float he1 = rlane(hh.x, l + 1), ho1 = rlane(hh.y, l + 1);
                    a0 = fmaf(wrow[2*l],     he0, a0);
                    a1 = fmaf(wrow[2*l + 1], ho0, a1);
                    a2 = fmaf(wrow[2*l + 2], he1, a2);
                    a3 = fmaf(wrow[2*l + 3], ho1, a3);
                }
                xp2buf[(s - 1) & 1][lane] = (a0 + a1) + (a2 + a3);  // xp2[s-1]+bias
            }
        } else {
            if (s >= 3) {
                float xv = xp2buf[s & 1][lane];   // = xp2[s-2] + bias
                float a0 = 0.f, a1 = 0.f, a2 = 0.f, a3 = 0.f;
#pragma unroll
                for (int l = 0; l < 64; l += 4) {
                    a0 = fmaf(wrow[l],     rlane(h2prev, l),     a0);
                    a1 = fmaf(wrow[l + 1], rlane(h2prev, l + 1), a1);
                    a2 = fmaf(wrow[l + 2], rlane(h2prev, l + 2), a2);
                    a3 = fmaf(wrow[l + 3], rlane(h2prev, l + 3), a3);
                }
                h2prev = tanh_fast(xv + ((a0 + a1) + (a2 + a3)));  // h2[s-2]
            }
        }
        __syncthreads();
        cur = nxt;
    }

    // FC head, wave3 only: h2prev = H2[512] (one value per lane, 64 lanes)
    if (wv == 3) {
        float a = (lane < 32) ? bfc1[lane] : 0.0f;
#pragma unroll
        for (int k = 0; k < 64; ++k)
            a = fmaf(wfc[k], rlane(h2prev, k), a);
        float v = (lane < 32) ? fmaxf(a, 0.0f) * Wfc2[lane] : 0.0f;
#pragma unroll
        for (int off = 16; off > 0; off >>= 1) v += __shfl_down(v, off);
        if (lane == 0) out[b] = v + bfc2[0];
    }
}

extern "C" void kernel_launch(void* const* d_in, const int* in_sizes, int n_in,
                              void* d_out, int out_size, void* d_ws, size_t ws_size,
                              hipStream_t stream) {
    const float* x     = (const float*)d_in[0];
    const float* Wih1  = (const float*)d_in[1];
    const float* Whh1  = (const float*)d_in[2];
    const float* bih1  = (const float*)d_in[3];
    const float* bhh1  = (const float*)d_in[4];
    const float* Wih2  = (const float*)d_in[5];
    const float* Whh2  = (const float*)d_in[6];
    const float* bih2  = (const float*)d_in[7];
    const float* bhh2  = (const float*)d_in[8];
    const float* Wfc1  = (const float*)d_in[9];
    const float* bfc1  = (const float*)d_in[10];
    const float* Wfc2  = (const float*)d_in[11];
    const float* bfc2  = (const float*)d_in[12];
    float* outp = (float*)d_out;

    float* xp1 = (float*)d_ws;   // 32768 x 128 fp32 = 16 MB

    xp1_gemm<<<dim3((NB * TT) / 128), dim3(256), 0, stream>>>(x, Wih1, bih1, bhh1, xp1);
    rnn_scan<<<dim3(NB), dim3(256), 0, stream>>>(xp1, Whh1, Wih2, Whh2, bih2, bhh2,
                                                 Wfc1, bfc1, Wfc2, bfc2, outp);
}